// Round 22
// baseline (48.098 us; speedup 1.0000x reference)
//
#include <hip/hip_runtime.h>
#include <math.h>

#define NN 32
#define CC 512
#define PP 1024   // H*W
#define KK 64
static constexpr float EPS = 1e-12f;

typedef __attribute__((ext_vector_type(8))) short bf16x8;
typedef __attribute__((ext_vector_type(4))) float f32x4;
typedef __attribute__((ext_vector_type(4))) unsigned int u32x4;
union FragU { u32x4 u; bf16x8 h; };

// pack two fp32 into one u32 of 2 bf16 (RNE)
__device__ __forceinline__ unsigned int bfpair(float lo, float hi) {
    unsigned int ul = __builtin_bit_cast(unsigned int, lo);
    unsigned int uh = __builtin_bit_cast(unsigned int, hi);
    ul = ul + 0x7FFFu + ((ul >> 16) & 1u);
    uh = uh + 0x7FFFu + ((uh >> 16) & 1u);
    return (ul >> 16) | (uh & 0xFFFF0000u);
}

// ---------------- fused pixnorm + logits(MFMA) + softmax -> sab=(sa*iv) bf16, Spart ----------------
// grid: 256 blocks = n(32) x 128-px tile(8). 512 threads = 8 waves. (R21 verbatim)
__global__ void __launch_bounds__(512, 2) k_logits(
        const float* __restrict__ x, const float* __restrict__ w,
        const float* __restrict__ bias, unsigned int* __restrict__ sab,
        float* __restrict__ Spart) {
    int b = blockIdx.x;
    int n = b >> 3;
    int p0 = (b & 7) << 7;           // 128-px tile base
    int tid = threadIdx.x;
    int lane = tid & 63;
    int wv = __builtin_amdgcn_readfirstlane(tid >> 6);   // 0..7 = px tile
    int l15 = lane & 15, l4 = lane >> 4;
    int rp = tid >> 4;               // staging cpair row 0..31
    int px8 = (tid & 15) << 3;       // staging px octet

    __shared__ unsigned int smem_u[26240];   // 104960 B
    unsigned int* XP  = smem_u;              // 2 x [128][33] u32
    unsigned int* WBF = smem_u + 8448;       // [64][260] u32
    float* RED  = (float*)(smem_u + 25088);  // [8][128]
    float* REDI = (float*)(smem_u + 26112);  // [128]

    // ---- stage whole W (fp32 -> bf16 pairs) into LDS once ----
    {
        int k = tid >> 3, cb = (tid & 7) << 5;
        const float* wsrc = w + (k << 9) + (cb << 1);
#pragma unroll
        for (int i = 0; i < 8; ++i) {
            float4 f0 = *(const float4*)&wsrc[(i << 3)];
            float4 f1 = *(const float4*)&wsrc[(i << 3) + 4];
            u32x4 v;
            v[0] = bfpair(f0.x, f0.y); v[1] = bfpair(f0.z, f0.w);
            v[2] = bfpair(f1.x, f1.y); v[3] = bfpair(f1.z, f1.w);
            *(u32x4*)&WBF[k * 260 + cb + (i << 2)] = v;
        }
    }

    const float* xb = x + (size_t)n * CC * PP + p0;

    f32x4 c0v = {0.f, 0.f, 0.f, 0.f};
    f32x4 c1v = {0.f, 0.f, 0.f, 0.f};
    f32x4 c2v = {0.f, 0.f, 0.f, 0.f};
    f32x4 c3v = {0.f, 0.f, 0.f, 0.f};
    float ssq[8] = {};
    float4 a0, a1, b0, b1;

#define PFL(i) { const float* xa = xb + (size_t)((i) * 64 + 2 * rp) * PP + px8; \
        a0 = *(const float4*)xa; a1 = *(const float4*)(xa + 4); \
        b0 = *(const float4*)(xa + PP); b1 = *(const float4*)(xa + PP + 4); }

#define MSTEP(H) { \
        FragU bfr; \
        int ob = xo + ((H) << 4); \
        bfr.u[0] = xq[ob]; bfr.u[1] = xq[ob + 1]; \
        bfr.u[2] = xq[ob + 2]; bfr.u[3] = xq[ob + 3]; \
        int oa = l15 * 260 + (i << 5) + ((H) << 4) + (l4 << 2); \
        FragU af; \
        af.u = *(const u32x4*)&WBF[oa]; \
        c0v = __builtin_amdgcn_mfma_f32_16x16x32_bf16(af.h, bfr.h, c0v, 0, 0, 0); \
        af.u = *(const u32x4*)&WBF[oa + 4160]; \
        c1v = __builtin_amdgcn_mfma_f32_16x16x32_bf16(af.h, bfr.h, c1v, 0, 0, 0); \
        af.u = *(const u32x4*)&WBF[oa + 8320]; \
        c2v = __builtin_amdgcn_mfma_f32_16x16x32_bf16(af.h, bfr.h, c2v, 0, 0, 0); \
        af.u = *(const u32x4*)&WBF[oa + 12480]; \
        c3v = __builtin_amdgcn_mfma_f32_16x16x32_bf16(af.h, bfr.h, c3v, 0, 0, 0); \
    }

    PFL(0);
#pragma unroll 1
    for (int i = 0; i < 8; ++i) {
        __syncthreads();
        unsigned int* xp = XP + (i & 1) * 4224;
        float av[8] = {a0.x, a0.y, a0.z, a0.w, a1.x, a1.y, a1.z, a1.w};
        float bv[8] = {b0.x, b0.y, b0.z, b0.w, b1.x, b1.y, b1.z, b1.w};
#pragma unroll
        for (int j = 0; j < 8; ++j) {
            xp[(px8 + j) * 33 + rp] = bfpair(av[j], bv[j]);
            ssq[j] = fmaf(av[j], av[j], fmaf(bv[j], bv[j], ssq[j]));
        }
        __syncthreads();
        if (i < 7) { PFL(i + 1); }
        const unsigned int* xq = XP + (i & 1) * 4224;
        int xo = (wv * 16 + l15) * 33 + (l4 << 2);
        MSTEP(0);
        MSTEP(1);
    }
#undef PFL
#undef MSTEP

#pragma unroll
    for (int j = 0; j < 8; ++j) {
        ssq[j] += __shfl_xor(ssq[j], 16);
        ssq[j] += __shfl_xor(ssq[j], 32);
    }
    if (l4 == 0) {
#pragma unroll
        for (int j = 0; j < 8; ++j) RED[(wv << 7) + px8 + j] = ssq[j];
    }
    __syncthreads();
    if (tid < 128) {
        float s = 0.f;
#pragma unroll
        for (int w8 = 0; w8 < 8; ++w8) s += RED[(w8 << 7) + tid];
        REDI[tid] = 1.0f / fmaxf(sqrtf(s), EPS);
    }
    __syncthreads();

    float inv = REDI[(wv << 4) + l15];
    float lg[16];
#pragma unroll
    for (int r = 0; r < 4; ++r) {
        lg[r]      = c0v[r];
        lg[4 + r]  = c1v[r];
        lg[8 + r]  = c2v[r];
        lg[12 + r] = c3v[r];
    }
    float m = -1e30f;
#pragma unroll
    for (int kk = 0; kk < 16; ++kk) {
        int k = ((kk >> 2) << 4) + (l4 << 2) + (kk & 3);
        lg[kk] = fmaf(lg[kk], inv, bias[k]);
        m = fmaxf(m, lg[kk]);
    }
    m = fmaxf(m, __shfl_xor(m, 16));
    m = fmaxf(m, __shfl_xor(m, 32));
    float sm = 0.f;
#pragma unroll
    for (int kk = 0; kk < 16; ++kk) {
        lg[kk] = __expf(lg[kk] - m);
        sm += lg[kk];
    }
    sm += __shfl_xor(sm, 16);
    sm += __shfl_xor(sm, 32);
    float si = 1.0f / sm;

    int pcol = p0 + (wv << 4) + l15;
#pragma unroll
    for (int kk = 0; kk < 16; ++kk) {
        int k = ((kk >> 2) << 4) + (l4 << 2) + (kk & 3);
        float v = lg[kk] * si;
        float vs = v;
        vs += __shfl_xor(vs, 1);
        vs += __shfl_xor(vs, 2);
        vs += __shfl_xor(vs, 4);
        vs += __shfl_xor(vs, 8);
        float vi = v * inv;
        float vh = __shfl_xor(vi, 1);
        if ((l15 & 1) == 0)
            sab[(((size_t)(n * KK + k) << 10) + pcol) >> 1] = bfpair(vi, vh);
        if (l15 == 0) RED[(wv << 6) + k] = vs;
    }
    __syncthreads();
    if (tid < 64) {
        float s = 0.f;
#pragma unroll
        for (int w8 = 0; w8 < 8; ++w8) s += RED[(w8 << 6) + tid];
        Spart[(((b & 7) * NN) + n) * KK + tid] = s;
    }
}

// ---------------- vlad[n][k][c] (MFMA) — 32-wide c tiles, 2 blocks/CU ----------------
// grid: 512 blocks; nb = b&31, ct = b>>5 (0..15, 32-c tile). b mod 8 = nb mod 8 ->
// all 16 sab-sharing blocks of one n stay on one XCD. 512 threads = 8 waves:
// wave = cs(2, 16-c subtile) x kt(4, 16-k tile); acc0 only (16k x 16c per wave).
// 4 chunks of 256 px, dbuf XT[32][129] (33.5KB LDS). A-frags direct from L2.
__global__ void __launch_bounds__(512, 2) k_vlad(
        const float* __restrict__ x, const unsigned int* __restrict__ sab,
        const float* __restrict__ Spart, const float* __restrict__ cent,
        float* __restrict__ vlad, float* __restrict__ ssqpart) {
    int b = blockIdx.x;
    int nb = b & 31;
    int ct = b >> 5;               // 0..15
    int c0 = ct << 5;
    int tid = threadIdx.x;
    int lane = tid & 63;
    int wv = __builtin_amdgcn_readfirstlane(tid >> 6);   // 0..7
    int l15 = lane & 15, l4 = lane >> 4;
    int kt = wv & 3;
    int cs = wv >> 2;              // 0..1

    __shared__ unsigned int smem_u[8384];    // 33536 B: 2 x XT[32][129] + R2
    float* R2 = (float*)(smem_u + 8256);     // [8][16]

    const float* xp = x + ((size_t)(nb * CC + c0) << 10);
    const unsigned int* arow = sab + ((size_t)(nb * KK + kt * 16 + l15) << 9) + (l4 << 2);

    f32x4 acc0 = {0.f, 0.f, 0.f, 0.f};

    float4 xA[4], xB[4];
    u32x4 aA[8], aB[8];

#define LOADV(XS, AS, i) { \
        _Pragma("unroll") \
        for (int j = 0; j < 4; ++j) { \
            int r = (wv << 2) + j; \
            XS[j] = *(const float4*)(xp + ((size_t)r << 10) + ((i) << 8) + (lane << 2)); \
        } \
        _Pragma("unroll") \
        for (int j = 0; j < 8; ++j) AS[j] = *(const u32x4*)(arow + ((i) << 7) + (j << 4)); }

#define BODYV(XS, AS, i, LOADNEXT) { \
        __syncthreads(); \
        int bo = ((i) & 1) * 4128; \
        _Pragma("unroll") \
        for (int j = 0; j < 4; ++j) { \
            int r = (wv << 2) + j; \
            uint2 xw; \
            xw.x = bfpair(XS[j].x, XS[j].y); \
            xw.y = bfpair(XS[j].z, XS[j].w); \
            *(uint2*)(smem_u + bo + r * 129 + (lane << 1)) = xw; \
        } \
        __syncthreads(); \
        LOADNEXT; \
        _Pragma("unroll") \
        for (int ks = 0; ks < 8; ++ks) { \
            FragU af, bf0; \
            af.u  = AS[ks]; \
            bf0.u = *(const u32x4*)(smem_u + bo + (cs * 16 + l15) * 129 + (l4 << 2) + (ks << 4)); \
            acc0 = __builtin_amdgcn_mfma_f32_16x16x32_bf16(af.h, bf0.h, acc0, 0, 0, 0); \
        } }

    LOADV(xA, aA, 0);
    LOADV(xB, aB, 1);
    BODYV(xA, aA, 0, LOADV(xA, aA, 2));
    BODYV(xB, aB, 1, LOADV(xB, aB, 3));
    BODYV(xA, aA, 2, );
    BODYV(xB, aB, 3, );
#undef LOADV
#undef BODYV

    // ---- fused epilogue: vlad = acc - S*cent, row-sumsq partials -> ssqpart ----
#pragma unroll
    for (int r = 0; r < 4; ++r) {
        int k = kt * 16 + (l4 << 2) + r;
        float S = 0.f;
#pragma unroll
        for (int pt = 0; pt < 8; ++pt) S += Spart[(pt * NN + nb) * KK + k];
        int cg = c0 + cs * 16 + l15;
        float v0 = fmaf(-S, cent[(size_t)k * CC + cg], acc0[r]);
        vlad[((size_t)nb * KK + k) * CC + cg] = v0;
        float sq = v0 * v0;
        sq += __shfl_xor(sq, 1);
        sq += __shfl_xor(sq, 2);
        sq += __shfl_xor(sq, 4);
        sq += __shfl_xor(sq, 8);
        if (l15 == 0) R2[(wv << 4) + (l4 << 2) + r] = sq;
    }
    __syncthreads();
    if (tid < 64) {
        int kt2 = tid >> 4, kl = tid & 15;
        ssqpart[(ct * NN + nb) * KK + tid] =
            R2[(kt2 << 4) + kl] + R2[((kt2 + 4) << 4) + kl];
    }
}

// ---------------- final scale: rinv/tinv from ssqpart (16 partials), out = vlad*rinv*tinv ----------------
__global__ void k_final(const float* __restrict__ vlad, const float* __restrict__ ssqpart,
                        float* __restrict__ out) {
    size_t i4 = (size_t)blockIdx.x * 256 + threadIdx.x;
    int row = (int)(i4 >> 7);
    int n = row >> 6;
    int lane = threadIdx.x & 63;
    float s = 0.f;
#pragma unroll
    for (int ctile = 0; ctile < 16; ++ctile)
        s += ssqpart[(ctile * NN + n) * KK + lane];
    float iv = 1.0f / fmaxf(sqrtf(s), EPS);
    float rq = s * iv * iv;
#pragma unroll
    for (int off = 32; off > 0; off >>= 1) rq += __shfl_xor(rq, off);
    float tinv = 1.0f / fmaxf(sqrtf(rq), EPS);
    float rinv = __shfl(iv, row & 63);
    float4 v = ((const float4*)vlad)[i4];
    float sc = rinv * tinv;
    float4 o{v.x * sc, v.y * sc, v.z * sc, v.w * sc};
    ((float4*)out)[i4] = o;
}

extern "C" void kernel_launch(void* const* d_in, const int* in_sizes, int n_in,
                              void* d_out, int out_size, void* d_ws, size_t ws_size,
                              hipStream_t stream) {
    const float* x    = (const float*)d_in[0];
    const float* w    = (const float*)d_in[1];
    const float* bias = (const float*)d_in[2];
    const float* cent = (const float*)d_in[3];
    float* ws = (float*)d_ws;

    float* vlad    = ws;                              // 1048576
    float* Spart   = vlad + (size_t)NN * KK * CC;     // 16384
    float* ssqpart = Spart + 8 * NN * KK;             // 32768 (16 partials)
    unsigned int* sab = (unsigned int*)(ssqpart + 16 * NN * KK);   // 1048576 u32

    float* out = (float*)d_out;

    k_logits<<<dim3(256), dim3(512), 0, stream>>>(x, w, bias, sab, Spart);
    k_vlad<<<dim3(512), dim3(512), 0, stream>>>(x, sab, Spart, cent, vlad, ssqpart);
    k_final<<<dim3(1024), dim3(256), 0, stream>>>(vlad, ssqpart, out);
}

// Round 23
// 47.314 us; speedup vs baseline: 1.0166x; 1.0166x over previous
//
#include <hip/hip_runtime.h>
#include <math.h>

#define NN 32
#define CC 512
#define PP 1024   // H*W
#define KK 64
static constexpr float EPS = 1e-12f;

typedef __attribute__((ext_vector_type(8))) short bf16x8;
typedef __attribute__((ext_vector_type(4))) float f32x4;
typedef __attribute__((ext_vector_type(4))) unsigned int u32x4;
union FragU { u32x4 u; bf16x8 h; };

// pack two fp32 into one u32 of 2 bf16 (RNE)
__device__ __forceinline__ unsigned int bfpair(float lo, float hi) {
    unsigned int ul = __builtin_bit_cast(unsigned int, lo);
    unsigned int uh = __builtin_bit_cast(unsigned int, hi);
    ul = ul + 0x7FFFu + ((ul >> 16) & 1u);
    uh = uh + 0x7FFFu + ((uh >> 16) & 1u);
    return (ul >> 16) | (uh & 0xFFFF0000u);
}

// ---------------- fused pixnorm + logits(MFMA) + softmax -> sab=(sa*iv) bf16, Spart ----------------
// grid: 256 blocks = n(32) x 128-px tile(8). 512 threads = 8 waves. (R21 verbatim)
__global__ void __launch_bounds__(512, 2) k_logits(
        const float* __restrict__ x, const float* __restrict__ w,
        const float* __restrict__ bias, unsigned int* __restrict__ sab,
        float* __restrict__ Spart) {
    int b = blockIdx.x;
    int n = b >> 3;
    int p0 = (b & 7) << 7;           // 128-px tile base
    int tid = threadIdx.x;
    int lane = tid & 63;
    int wv = __builtin_amdgcn_readfirstlane(tid >> 6);   // 0..7 = px tile
    int l15 = lane & 15, l4 = lane >> 4;
    int rp = tid >> 4;               // staging cpair row 0..31
    int px8 = (tid & 15) << 3;       // staging px octet

    __shared__ unsigned int smem_u[26240];   // 104960 B
    unsigned int* XP  = smem_u;              // 2 x [128][33] u32
    unsigned int* WBF = smem_u + 8448;       // [64][260] u32
    float* RED  = (float*)(smem_u + 25088);  // [8][128]
    float* REDI = (float*)(smem_u + 26112);  // [128]

    // ---- stage whole W (fp32 -> bf16 pairs) into LDS once ----
    {
        int k = tid >> 3, cb = (tid & 7) << 5;
        const float* wsrc = w + (k << 9) + (cb << 1);
#pragma unroll
        for (int i = 0; i < 8; ++i) {
            float4 f0 = *(const float4*)&wsrc[(i << 3)];
            float4 f1 = *(const float4*)&wsrc[(i << 3) + 4];
            u32x4 v;
            v[0] = bfpair(f0.x, f0.y); v[1] = bfpair(f0.z, f0.w);
            v[2] = bfpair(f1.x, f1.y); v[3] = bfpair(f1.z, f1.w);
            *(u32x4*)&WBF[k * 260 + cb + (i << 2)] = v;
        }
    }

    const float* xb = x + (size_t)n * CC * PP + p0;

    f32x4 c0v = {0.f, 0.f, 0.f, 0.f};
    f32x4 c1v = {0.f, 0.f, 0.f, 0.f};
    f32x4 c2v = {0.f, 0.f, 0.f, 0.f};
    f32x4 c3v = {0.f, 0.f, 0.f, 0.f};
    float ssq[8] = {};
    float4 a0, a1, b0, b1;

#define PFL(i) { const float* xa = xb + (size_t)((i) * 64 + 2 * rp) * PP + px8; \
        a0 = *(const float4*)xa; a1 = *(const float4*)(xa + 4); \
        b0 = *(const float4*)(xa + PP); b1 = *(const float4*)(xa + PP + 4); }

#define MSTEP(H) { \
        FragU bfr; \
        int ob = xo + ((H) << 4); \
        bfr.u[0] = xq[ob]; bfr.u[1] = xq[ob + 1]; \
        bfr.u[2] = xq[ob + 2]; bfr.u[3] = xq[ob + 3]; \
        int oa = l15 * 260 + (i << 5) + ((H) << 4) + (l4 << 2); \
        FragU af; \
        af.u = *(const u32x4*)&WBF[oa]; \
        c0v = __builtin_amdgcn_mfma_f32_16x16x32_bf16(af.h, bfr.h, c0v, 0, 0, 0); \
        af.u = *(const u32x4*)&WBF[oa + 4160]; \
        c1v = __builtin_amdgcn_mfma_f32_16x16x32_bf16(af.h, bfr.h, c1v, 0, 0, 0); \
        af.u = *(const u32x4*)&WBF[oa + 8320]; \
        c2v = __builtin_amdgcn_mfma_f32_16x16x32_bf16(af.h, bfr.h, c2v, 0, 0, 0); \
        af.u = *(const u32x4*)&WBF[oa + 12480]; \
        c3v = __builtin_amdgcn_mfma_f32_16x16x32_bf16(af.h, bfr.h, c3v, 0, 0, 0); \
    }

    PFL(0);
#pragma unroll 1
    for (int i = 0; i < 8; ++i) {
        __syncthreads();
        unsigned int* xp = XP + (i & 1) * 4224;
        float av[8] = {a0.x, a0.y, a0.z, a0.w, a1.x, a1.y, a1.z, a1.w};
        float bv[8] = {b0.x, b0.y, b0.z, b0.w, b1.x, b1.y, b1.z, b1.w};
#pragma unroll
        for (int j = 0; j < 8; ++j) {
            xp[(px8 + j) * 33 + rp] = bfpair(av[j], bv[j]);
            ssq[j] = fmaf(av[j], av[j], fmaf(bv[j], bv[j], ssq[j]));
        }
        __syncthreads();
        if (i < 7) { PFL(i + 1); }
        const unsigned int* xq = XP + (i & 1) * 4224;
        int xo = (wv * 16 + l15) * 33 + (l4 << 2);
        MSTEP(0);
        MSTEP(1);
    }
#undef PFL
#undef MSTEP

#pragma unroll
    for (int j = 0; j < 8; ++j) {
        ssq[j] += __shfl_xor(ssq[j], 16);
        ssq[j] += __shfl_xor(ssq[j], 32);
    }
    if (l4 == 0) {
#pragma unroll
        for (int j = 0; j < 8; ++j) RED[(wv << 7) + px8 + j] = ssq[j];
    }
    __syncthreads();
    if (tid < 128) {
        float s = 0.f;
#pragma unroll
        for (int w8 = 0; w8 < 8; ++w8) s += RED[(w8 << 7) + tid];
        REDI[tid] = 1.0f / fmaxf(sqrtf(s), EPS);
    }
    __syncthreads();

    float inv = REDI[(wv << 4) + l15];
    float lg[16];
#pragma unroll
    for (int r = 0; r < 4; ++r) {
        lg[r]      = c0v[r];
        lg[4 + r]  = c1v[r];
        lg[8 + r]  = c2v[r];
        lg[12 + r] = c3v[r];
    }
    float m = -1e30f;
#pragma unroll
    for (int kk = 0; kk < 16; ++kk) {
        int k = ((kk >> 2) << 4) + (l4 << 2) + (kk & 3);
        lg[kk] = fmaf(lg[kk], inv, bias[k]);
        m = fmaxf(m, lg[kk]);
    }
    m = fmaxf(m, __shfl_xor(m, 16));
    m = fmaxf(m, __shfl_xor(m, 32));
    float sm = 0.f;
#pragma unroll
    for (int kk = 0; kk < 16; ++kk) {
        lg[kk] = __expf(lg[kk] - m);
        sm += lg[kk];
    }
    sm += __shfl_xor(sm, 16);
    sm += __shfl_xor(sm, 32);
    float si = 1.0f / sm;

    int pcol = p0 + (wv << 4) + l15;
#pragma unroll
    for (int kk = 0; kk < 16; ++kk) {
        int k = ((kk >> 2) << 4) + (l4 << 2) + (kk & 3);
        float v = lg[kk] * si;
        float vs = v;
        vs += __shfl_xor(vs, 1);
        vs += __shfl_xor(vs, 2);
        vs += __shfl_xor(vs, 4);
        vs += __shfl_xor(vs, 8);
        float vi = v * inv;
        float vh = __shfl_xor(vi, 1);
        if ((l15 & 1) == 0)
            sab[(((size_t)(n * KK + k) << 10) + pcol) >> 1] = bfpair(vi, vh);
        if (l15 == 0) RED[(wv << 6) + k] = vs;
    }
    __syncthreads();
    if (tid < 64) {
        float s = 0.f;
#pragma unroll
        for (int w8 = 0; w8 < 8; ++w8) s += RED[(w8 << 6) + tid];
        Spart[(((b & 7) * NN) + n) * KK + tid] = s;
    }
}

// ---------------- vlad[n][k][c] (MFMA) — R21 structure + 2 blocks/CU ----------------
// grid: 256 blocks; nb = b&31, ct = b>>5. 512 threads = 8 waves; 4 chunks of 256 px,
// dbuf XT[64][129] (66KB LDS). x prefetched (wave-contiguous float4 rows);
// A-frags loaded DIRECTLY from L2 inside the MFMA loop (no prefetch arrays) ->
// VGPR ~95, fits __launch_bounds__(512,2) -> 2 blocks/CU latency hiding.
__global__ void __launch_bounds__(512, 2) k_vlad(
        const float* __restrict__ x, const unsigned int* __restrict__ sab,
        const float* __restrict__ Spart, const float* __restrict__ cent,
        float* __restrict__ vlad, float* __restrict__ ssqpart) {
    int b = blockIdx.x;
    int nb = b & 31;
    int ct = b >> 5;
    int c0 = ct << 6;
    int tid = threadIdx.x;
    int lane = tid & 63;
    int wv = __builtin_amdgcn_readfirstlane(tid >> 6);   // 0..7
    int l15 = lane & 15, l4 = lane >> 4;
    int kt = wv & 3;
    int ctb = (wv >> 2) << 1;      // 0 or 2

    __shared__ unsigned int smem_u[16640];   // 66560 B: 2 x XT[64][129] + R2
    float* R2 = (float*)(smem_u + 16512);    // [8][16]

    const float* xp = x + ((size_t)(nb * CC + c0) << 10);
    const unsigned int* arow = sab + ((size_t)(nb * KK + kt * 16 + l15) << 9) + (l4 << 2);

    f32x4 acc0 = {0.f, 0.f, 0.f, 0.f};
    f32x4 acc1 = {0.f, 0.f, 0.f, 0.f};

    float4 xA[8], xB[8];

#define LOADV(XS, i) { \
        _Pragma("unroll") \
        for (int j = 0; j < 8; ++j) { \
            int r = (wv << 3) + j; \
            XS[j] = *(const float4*)(xp + ((size_t)r << 10) + ((i) << 8) + (lane << 2)); \
        } }

#define BODYV(XS, i, LOADNEXT) { \
        __syncthreads(); \
        int bo = ((i) & 1) * 8256; \
        _Pragma("unroll") \
        for (int j = 0; j < 8; ++j) { \
            int r = (wv << 3) + j; \
            uint2 xw; \
            xw.x = bfpair(XS[j].x, XS[j].y); \
            xw.y = bfpair(XS[j].z, XS[j].w); \
            *(uint2*)(smem_u + bo + r * 129 + (lane << 1)) = xw; \
        } \
        __syncthreads(); \
        LOADNEXT; \
        _Pragma("unroll") \
        for (int ks = 0; ks < 8; ++ks) { \
            FragU af, bf0, bf1; \
            af.u  = *(const u32x4*)(arow + ((i) << 7) + (ks << 4)); \
            bf0.u = *(const u32x4*)(smem_u + bo + (ctb * 16 + l15) * 129 + (l4 << 2) + (ks << 4)); \
            bf1.u = *(const u32x4*)(smem_u + bo + ((ctb + 1) * 16 + l15) * 129 + (l4 << 2) + (ks << 4)); \
            acc0 = __builtin_amdgcn_mfma_f32_16x16x32_bf16(af.h, bf0.h, acc0, 0, 0, 0); \
            acc1 = __builtin_amdgcn_mfma_f32_16x16x32_bf16(af.h, bf1.h, acc1, 0, 0, 0); \
        } }

    LOADV(xA, 0);
    LOADV(xB, 1);
    BODYV(xA, 0, LOADV(xA, 2));
    BODYV(xB, 1, LOADV(xB, 3));
    BODYV(xA, 2, );
    BODYV(xB, 3, );
#undef LOADV
#undef BODYV

    // ---- fused epilogue: vlad = acc - S*cent, row-sumsq partials -> ssqpart ----
#pragma unroll
    for (int r = 0; r < 4; ++r) {
        int k = kt * 16 + (l4 << 2) + r;
        float S = 0.f;
#pragma unroll
        for (int pt = 0; pt < 8; ++pt) S += Spart[(pt * NN + nb) * KK + k];
        int cg = c0 + ctb * 16 + l15;
        const float* cp = cent + (size_t)k * CC + cg;
        float v0 = fmaf(-S, cp[0],  acc0[r]);
        float v1 = fmaf(-S, cp[16], acc1[r]);
        float* vp = vlad + ((size_t)nb * KK + k) * CC + cg;
        vp[0]  = v0;
        vp[16] = v1;
        float sq = fmaf(v0, v0, v1 * v1);
        sq += __shfl_xor(sq, 1);
        sq += __shfl_xor(sq, 2);
        sq += __shfl_xor(sq, 4);
        sq += __shfl_xor(sq, 8);
        if (l15 == 0) R2[(wv << 4) + (l4 << 2) + r] = sq;
    }
    __syncthreads();
    if (tid < 64) {
        int kt2 = tid >> 4, kl = tid & 15;
        ssqpart[(ct * NN + nb) * KK + tid] =
            R2[(kt2 << 4) + kl] + R2[((kt2 + 4) << 4) + kl];
    }
}

// ---------------- final scale: rinv/tinv from ssqpart, out = vlad*rinv*tinv ----------------
__global__ void k_final(const float* __restrict__ vlad, const float* __restrict__ ssqpart,
                        float* __restrict__ out) {
    size_t i4 = (size_t)blockIdx.x * 256 + threadIdx.x;
    int row = (int)(i4 >> 7);
    int n = row >> 6;
    int lane = threadIdx.x & 63;
    float s = 0.f;
#pragma unroll
    for (int ctile = 0; ctile < 8; ++ctile)
        s += ssqpart[(ctile * NN + n) * KK + lane];
    float iv = 1.0f / fmaxf(sqrtf(s), EPS);
    float rq = s * iv * iv;
#pragma unroll
    for (int off = 32; off > 0; off >>= 1) rq += __shfl_xor(rq, off);
    float tinv = 1.0f / fmaxf(sqrtf(rq), EPS);
    float rinv = __shfl(iv, row & 63);
    float4 v = ((const float4*)vlad)[i4];
    float sc = rinv * tinv;
    float4 o{v.x * sc, v.y * sc, v.z * sc, v.w * sc};
    ((float4*)out)[i4] = o;
}

extern "C" void kernel_launch(void* const* d_in, const int* in_sizes, int n_in,
                              void* d_out, int out_size, void* d_ws, size_t ws_size,
                              hipStream_t stream) {
    const float* x    = (const float*)d_in[0];
    const float* w    = (const float*)d_in[1];
    const float* bias = (const float*)d_in[2];
    const float* cent = (const float*)d_in[3];
    float* ws = (float*)d_ws;

    float* vlad    = ws;                              // 1048576
    float* Spart   = vlad + (size_t)NN * KK * CC;     // 16384
    float* ssqpart = Spart + 8 * NN * KK;             // 16384
    unsigned int* sab = (unsigned int*)(ssqpart + 8 * NN * KK);   // 1048576 u32

    float* out = (float*)d_out;

    k_logits<<<dim3(256), dim3(512), 0, stream>>>(x, w, bias, sab, Spart);
    k_vlad<<<dim3(256), dim3(512), 0, stream>>>(x, sab, Spart, cent, vlad, ssqpart);
    k_final<<<dim3(1024), dim3(256), 0, stream>>>(vlad, ssqpart, out);
}

// Round 24
// 45.541 us; speedup vs baseline: 1.0561x; 1.0389x over previous
//
#include <hip/hip_runtime.h>
#include <math.h>

#define NN 32
#define CC 512
#define PP 1024   // H*W
#define KK 64
static constexpr float EPS = 1e-12f;

typedef __attribute__((ext_vector_type(8))) short bf16x8;
typedef __attribute__((ext_vector_type(4))) float f32x4;
typedef __attribute__((ext_vector_type(4))) unsigned int u32x4;
union FragU { u32x4 u; bf16x8 h; };

// pack two fp32 into one u32 of 2 bf16 (RNE)
__device__ __forceinline__ unsigned int bfpair(float lo, float hi) {
    unsigned int ul = __builtin_bit_cast(unsigned int, lo);
    unsigned int uh = __builtin_bit_cast(unsigned int, hi);
    ul = ul + 0x7FFFu + ((ul >> 16) & 1u);
    uh = uh + 0x7FFFu + ((uh >> 16) & 1u);
    return (ul >> 16) | (uh & 0xFFFF0000u);
}

// ---------------- fused pixnorm + logits(MFMA) + softmax -> sab=(sa*iv) bf16, Spart ----------------
// grid: 256 blocks = n(32) x 128-px tile(8). 512 threads = 8 waves.
__global__ void __launch_bounds__(512, 2) k_logits(
        const float* __restrict__ x, const float* __restrict__ w,
        const float* __restrict__ bias, unsigned int* __restrict__ sab,
        float* __restrict__ Spart) {
    int b = blockIdx.x;
    int n = b >> 3;
    int p0 = (b & 7) << 7;           // 128-px tile base
    int tid = threadIdx.x;
    int lane = tid & 63;
    int wv = __builtin_amdgcn_readfirstlane(tid >> 6);   // 0..7 = px tile
    int l15 = lane & 15, l4 = lane >> 4;
    int rp = tid >> 4;               // staging cpair row 0..31
    int px8 = (tid & 15) << 3;       // staging px octet

    __shared__ unsigned int smem_u[26240];   // 104960 B
    unsigned int* XP  = smem_u;              // 2 x [128][33] u32
    unsigned int* WBF = smem_u + 8448;       // [64][260] u32
    float* RED  = (float*)(smem_u + 25088);  // [8][128]
    float* REDI = (float*)(smem_u + 26112);  // [128]

    // ---- stage whole W (fp32 -> bf16 pairs) into LDS once ----
    {
        int k = tid >> 3, cb = (tid & 7) << 5;
        const float* wsrc = w + (k << 9) + (cb << 1);
#pragma unroll
        for (int i = 0; i < 8; ++i) {
            float4 f0 = *(const float4*)&wsrc[(i << 3)];
            float4 f1 = *(const float4*)&wsrc[(i << 3) + 4];
            u32x4 v;
            v[0] = bfpair(f0.x, f0.y); v[1] = bfpair(f0.z, f0.w);
            v[2] = bfpair(f1.x, f1.y); v[3] = bfpair(f1.z, f1.w);
            *(u32x4*)&WBF[k * 260 + cb + (i << 2)] = v;
        }
    }

    const float* xb = x + (size_t)n * CC * PP + p0;

    f32x4 c0v = {0.f, 0.f, 0.f, 0.f};
    f32x4 c1v = {0.f, 0.f, 0.f, 0.f};
    f32x4 c2v = {0.f, 0.f, 0.f, 0.f};
    f32x4 c3v = {0.f, 0.f, 0.f, 0.f};
    float ssq[8] = {};
    float4 a0, a1, b0, b1;

#define PFL(i) { const float* xa = xb + (size_t)((i) * 64 + 2 * rp) * PP + px8; \
        a0 = *(const float4*)xa; a1 = *(const float4*)(xa + 4); \
        b0 = *(const float4*)(xa + PP); b1 = *(const float4*)(xa + PP + 4); }

#define MSTEP(H) { \
        FragU bfr; \
        int ob = xo + ((H) << 4); \
        bfr.u[0] = xq[ob]; bfr.u[1] = xq[ob + 1]; \
        bfr.u[2] = xq[ob + 2]; bfr.u[3] = xq[ob + 3]; \
        int oa = l15 * 260 + (i << 5) + ((H) << 4) + (l4 << 2); \
        FragU af; \
        af.u = *(const u32x4*)&WBF[oa]; \
        c0v = __builtin_amdgcn_mfma_f32_16x16x32_bf16(af.h, bfr.h, c0v, 0, 0, 0); \
        af.u = *(const u32x4*)&WBF[oa + 4160]; \
        c1v = __builtin_amdgcn_mfma_f32_16x16x32_bf16(af.h, bfr.h, c1v, 0, 0, 0); \
        af.u = *(const u32x4*)&WBF[oa + 8320]; \
        c2v = __builtin_amdgcn_mfma_f32_16x16x32_bf16(af.h, bfr.h, c2v, 0, 0, 0); \
        af.u = *(const u32x4*)&WBF[oa + 12480]; \
        c3v = __builtin_amdgcn_mfma_f32_16x16x32_bf16(af.h, bfr.h, c3v, 0, 0, 0); \
    }

    PFL(0);
#pragma unroll 1
    for (int i = 0; i < 8; ++i) {
        __syncthreads();
        unsigned int* xp = XP + (i & 1) * 4224;
        float av[8] = {a0.x, a0.y, a0.z, a0.w, a1.x, a1.y, a1.z, a1.w};
        float bv[8] = {b0.x, b0.y, b0.z, b0.w, b1.x, b1.y, b1.z, b1.w};
#pragma unroll
        for (int j = 0; j < 8; ++j) {
            xp[(px8 + j) * 33 + rp] = bfpair(av[j], bv[j]);
            ssq[j] = fmaf(av[j], av[j], fmaf(bv[j], bv[j], ssq[j]));
        }
        __syncthreads();
        if (i < 7) { PFL(i + 1); }
        const unsigned int* xq = XP + (i & 1) * 4224;
        int xo = (wv * 16 + l15) * 33 + (l4 << 2);
        MSTEP(0);
        MSTEP(1);
    }
#undef PFL
#undef MSTEP

#pragma unroll
    for (int j = 0; j < 8; ++j) {
        ssq[j] += __shfl_xor(ssq[j], 16);
        ssq[j] += __shfl_xor(ssq[j], 32);
    }
    if (l4 == 0) {
#pragma unroll
        for (int j = 0; j < 8; ++j) RED[(wv << 7) + px8 + j] = ssq[j];
    }
    __syncthreads();
    if (tid < 128) {
        float s = 0.f;
#pragma unroll
        for (int w8 = 0; w8 < 8; ++w8) s += RED[(w8 << 7) + tid];
        REDI[tid] = 1.0f / fmaxf(sqrtf(s), EPS);
    }
    __syncthreads();

    float inv = REDI[(wv << 4) + l15];
    float lg[16];
#pragma unroll
    for (int r = 0; r < 4; ++r) {
        lg[r]      = c0v[r];
        lg[4 + r]  = c1v[r];
        lg[8 + r]  = c2v[r];
        lg[12 + r] = c3v[r];
    }
    float m = -1e30f;
#pragma unroll
    for (int kk = 0; kk < 16; ++kk) {
        int k = ((kk >> 2) << 4) + (l4 << 2) + (kk & 3);
        lg[kk] = fmaf(lg[kk], inv, bias[k]);
        m = fmaxf(m, lg[kk]);
    }
    m = fmaxf(m, __shfl_xor(m, 16));
    m = fmaxf(m, __shfl_xor(m, 32));
    float sm = 0.f;
#pragma unroll
    for (int kk = 0; kk < 16; ++kk) {
        lg[kk] = __expf(lg[kk] - m);
        sm += lg[kk];
    }
    sm += __shfl_xor(sm, 16);
    sm += __shfl_xor(sm, 32);
    float si = 1.0f / sm;

    int pcol = p0 + (wv << 4) + l15;
#pragma unroll
    for (int kk = 0; kk < 16; ++kk) {
        int k = ((kk >> 2) << 4) + (l4 << 2) + (kk & 3);
        float v = lg[kk] * si;
        float vs = v;
        vs += __shfl_xor(vs, 1);
        vs += __shfl_xor(vs, 2);
        vs += __shfl_xor(vs, 4);
        vs += __shfl_xor(vs, 8);
        float vi = v * inv;
        float vh = __shfl_xor(vi, 1);
        if ((l15 & 1) == 0)
            sab[(((size_t)(n * KK + k) << 10) + pcol) >> 1] = bfpair(vi, vh);
        if (l15 == 0) RED[(wv << 6) + k] = vs;
    }
    __syncthreads();
    if (tid < 64) {
        float s = 0.f;
#pragma unroll
        for (int w8 = 0; w8 < 8; ++w8) s += RED[(w8 << 6) + tid];
        Spart[(((b & 7) * NN) + n) * KK + tid] = s;
    }
}

// ---------------- vlad[n][k][c] (MFMA) — wave-contiguous x staging; A-frags prefetched from L2 ----------------
// grid: 256 blocks; nb = b&31, ct = b>>5 (same-nb blocks share an XCD -> sab L2-hot).
// 512 threads = 8 waves. 4 chunks of 256 px, double-buffered XT only (66KB LDS).
// A-fragments (sab) prefetched straight into registers (8 x u32x4 per chunk).
__global__ void __launch_bounds__(512) k_vlad(
        const float* __restrict__ x, const unsigned int* __restrict__ sab,
        const float* __restrict__ Spart, const float* __restrict__ cent,
        float* __restrict__ vlad, float* __restrict__ ssqpart) {
    int b = blockIdx.x;
    int nb = b & 31;
    int ct = b >> 5;
    int c0 = ct << 6;
    int tid = threadIdx.x;
    int lane = tid & 63;
    int wv = __builtin_amdgcn_readfirstlane(tid >> 6);   // 0..7
    int l15 = lane & 15, l4 = lane >> 4;
    int kt = wv & 3;
    int ctb = (wv >> 2) << 1;      // 0 or 2

    __shared__ unsigned int smem_u[16640];   // 66560 B: 2 x XT[64][129] + R2
    float* R2 = (float*)(smem_u + 16512);    // [8][16]

    const float* xp = x + ((size_t)(nb * CC + c0) << 10);
    const unsigned int* arow = sab + ((size_t)(nb * KK + kt * 16 + l15) << 9) + (l4 << 2);

    f32x4 acc0 = {0.f, 0.f, 0.f, 0.f};
    f32x4 acc1 = {0.f, 0.f, 0.f, 0.f};

    float4 xA[8], xB[8];
    u32x4 aA[8], aB[8];

#define LOADV(XS, AS, i) { \
        _Pragma("unroll") \
        for (int j = 0; j < 8; ++j) { \
            int r = (wv << 3) + j; \
            XS[j] = *(const float4*)(xp + ((size_t)r << 10) + ((i) << 8) + (lane << 2)); \
            AS[j] = *(const u32x4*)(arow + ((i) << 7) + (j << 4)); \
        } }

#define BODYV(XS, AS, i, LOADNEXT) { \
        __syncthreads(); \
        int bo = ((i) & 1) * 8256; \
        _Pragma("unroll") \
        for (int j = 0; j < 8; ++j) { \
            int r = (wv << 3) + j; \
            uint2 xw; \
            xw.x = bfpair(XS[j].x, XS[j].y); \
            xw.y = bfpair(XS[j].z, XS[j].w); \
            *(uint2*)(smem_u + bo + r * 129 + (lane << 1)) = xw; \
        } \
        __syncthreads(); \
        LOADNEXT; \
        _Pragma("unroll") \
        for (int ks = 0; ks < 8; ++ks) { \
            FragU af, bf0, bf1; \
            af.u  = AS[ks]; \
            bf0.u = *(const u32x4*)(smem_u + bo + (ctb * 16 + l15) * 129 + (l4 << 2) + (ks << 4)); \
            bf1.u = *(const u32x4*)(smem_u + bo + ((ctb + 1) * 16 + l15) * 129 + (l4 << 2) + (ks << 4)); \
            acc0 = __builtin_amdgcn_mfma_f32_16x16x32_bf16(af.h, bf0.h, acc0, 0, 0, 0); \
            acc1 = __builtin_amdgcn_mfma_f32_16x16x32_bf16(af.h, bf1.h, acc1, 0, 0, 0); \
        } }

    LOADV(xA, aA, 0);
    LOADV(xB, aB, 1);
    BODYV(xA, aA, 0, LOADV(xA, aA, 2));
    BODYV(xB, aB, 1, LOADV(xB, aB, 3));
    BODYV(xA, aA, 2, );
    BODYV(xB, aB, 3, );
#undef LOADV
#undef BODYV

    // ---- fused epilogue: vlad = acc - S*cent, row-sumsq partials -> ssqpart ----
#pragma unroll
    for (int r = 0; r < 4; ++r) {
        int k = kt * 16 + (l4 << 2) + r;
        float S = 0.f;
#pragma unroll
        for (int pt = 0; pt < 8; ++pt) S += Spart[(pt * NN + nb) * KK + k];
        int cg = c0 + ctb * 16 + l15;
        const float* cp = cent + (size_t)k * CC + cg;
        float v0 = fmaf(-S, cp[0],  acc0[r]);
        float v1 = fmaf(-S, cp[16], acc1[r]);
        float* vp = vlad + ((size_t)nb * KK + k) * CC + cg;
        vp[0]  = v0;
        vp[16] = v1;
        float sq = fmaf(v0, v0, v1 * v1);
        sq += __shfl_xor(sq, 1);
        sq += __shfl_xor(sq, 2);
        sq += __shfl_xor(sq, 4);
        sq += __shfl_xor(sq, 8);
        if (l15 == 0) R2[(wv << 4) + (l4 << 2) + r] = sq;
    }
    __syncthreads();
    if (tid < 64) {
        int kt2 = tid >> 4, kl = tid & 15;
        ssqpart[(ct * NN + nb) * KK + tid] =
            R2[(kt2 << 4) + kl] + R2[((kt2 + 4) << 4) + kl];
    }
}

// ---------------- final scale: rinv/tinv from ssqpart, out = vlad*rinv*tinv ----------------
__global__ void k_final(const float* __restrict__ vlad, const float* __restrict__ ssqpart,
                        float* __restrict__ out) {
    size_t i4 = (size_t)blockIdx.x * 256 + threadIdx.x;
    int row = (int)(i4 >> 7);
    int n = row >> 6;
    int lane = threadIdx.x & 63;
    float s = 0.f;
#pragma unroll
    for (int ctile = 0; ctile < 8; ++ctile)
        s += ssqpart[(ctile * NN + n) * KK + lane];
    float iv = 1.0f / fmaxf(sqrtf(s), EPS);
    float rq = s * iv * iv;
#pragma unroll
    for (int off = 32; off > 0; off >>= 1) rq += __shfl_xor(rq, off);
    float tinv = 1.0f / fmaxf(sqrtf(rq), EPS);
    float rinv = __shfl(iv, row & 63);
    float4 v = ((const float4*)vlad)[i4];
    float sc = rinv * tinv;
    float4 o{v.x * sc, v.y * sc, v.z * sc, v.w * sc};
    ((float4*)out)[i4] = o;
}

extern "C" void kernel_launch(void* const* d_in, const int* in_sizes, int n_in,
                              void* d_out, int out_size, void* d_ws, size_t ws_size,
                              hipStream_t stream) {
    const float* x    = (const float*)d_in[0];
    const float* w    = (const float*)d_in[1];
    const float* bias = (const float*)d_in[2];
    const float* cent = (const float*)d_in[3];
    float* ws = (float*)d_ws;

    float* vlad    = ws;                              // 1048576
    float* Spart   = vlad + (size_t)NN * KK * CC;     // 16384
    float* ssqpart = Spart + 8 * NN * KK;             // 16384
    unsigned int* sab = (unsigned int*)(ssqpart + 8 * NN * KK);   // 1048576 u32

    float* out = (float*)d_out;

    k_logits<<<dim3(256), dim3(512), 0, stream>>>(x, w, bias, sab, Spart);
    k_vlad<<<dim3(256), dim3(512), 0, stream>>>(x, sab, Spart, cent, vlad, ssqpart);
    k_final<<<dim3(1024), dim3(256), 0, stream>>>(vlad, ssqpart, out);
}